// Round 8
// baseline (314.162 us; speedup 1.0000x reference)
//
#include <hip/hip_runtime.h>
#include <hip/hip_bf16.h>

#define N_NODES 100000
#define N_EDGES 800000
#define D 128
#define NG 64
#define SCAN_NB ((N_NODES + 255) / 256)   // 391
#define NTILES ((N_NODES + 63) / 64)      // 1563

typedef __attribute__((ext_vector_type(8))) short short8;
typedef __attribute__((ext_vector_type(4))) float f32x4;
typedef __attribute__((ext_vector_type(2))) float f32x2;

static __device__ __forceinline__ unsigned short f2bf(float f) {
    unsigned u = __float_as_uint(f);
    unsigned r = (u + 0x7FFF + ((u >> 16) & 1)) >> 16;   // RTN-even
    return (unsigned short)r;
}
static __device__ __forceinline__ float bf2f(unsigned short b) {
    return __uint_as_float((unsigned)b << 16);
}
static __device__ __forceinline__ unsigned char f2fp8(float v) {
    int p = __builtin_amdgcn_cvt_pk_fp8_f32(v, v, 0, false);  // RNE, OCP e4m3fn
    return (unsigned char)(p & 0xFF);
}

// ---------------- CSR build: histogram / scan(+dinv) / fill ----------------

__global__ void hist_kernel(const int* __restrict__ dst, int* __restrict__ deg) {
    int e = blockIdx.x * blockDim.x + threadIdx.x;
    if (e < N_EDGES) atomicAdd(&deg[dst[e]], 1);
}

// writes exclusive prefix into rs[i+1]; rs[0] set by scan3.
__global__ __launch_bounds__(256) void scan1_kernel(const int* __restrict__ deg,
                                                    int* __restrict__ rs,
                                                    int* __restrict__ bsum,
                                                    float* __restrict__ dinv) {
    __shared__ int wsum[4];
    int i = blockIdx.x * 256 + threadIdx.x;
    int lane = threadIdx.x & 63;
    int wid = threadIdx.x >> 6;
    int v = (i < N_NODES) ? deg[i] : 0;
    if (i < N_NODES) dinv[i] = rsqrtf((float)v + 1.0f);  // +1 self loop
    int x = v;
    #pragma unroll
    for (int off = 1; off < 64; off <<= 1) {
        int y = __shfl_up(x, off);
        if (lane >= off) x += y;
    }
    if (lane == 63) wsum[wid] = x;
    __syncthreads();
    int add = 0;
    #pragma unroll
    for (int w = 0; w < 3; ++w) if (w < wid) add += wsum[w];
    int incl = x + add;
    if (i < N_NODES) rs[i + 1] = incl - v;
    if (threadIdx.x == 255) bsum[blockIdx.x] = incl;
}

__global__ __launch_bounds__(512) void scan2_kernel(int* __restrict__ bsum) {
    __shared__ int s[512];
    int t = threadIdx.x;
    int v = (t < SCAN_NB) ? bsum[t] : 0;
    s[t] = v;
    __syncthreads();
    for (int off = 1; off < 512; off <<= 1) {
        int y = (t >= off) ? s[t - off] : 0;
        __syncthreads();
        s[t] += y;
        __syncthreads();
    }
    if (t < SCAN_NB) bsum[t] = s[t] - v;
}

__global__ void scan3_kernel(int* __restrict__ rs, const int* __restrict__ bsum) {
    int i = blockIdx.x * blockDim.x + threadIdx.x;
    if (i < N_NODES) rs[i + 1] += bsum[i >> 8];
    if (i == 0) rs[0] = 0;
}

// rs[1+d] doubles as the cursor: atomicAdd returns the slot. Post-fill,
// rs[i] = original start[i] for i in 0..N, so gather indexes rs[node]/rs[node+1].
__global__ void fill_kernel(const int* __restrict__ src, const int* __restrict__ dst,
                            int* __restrict__ rs, int* __restrict__ pairs) {
    int e = blockIdx.x * blockDim.x + threadIdx.x;
    if (e < N_EDGES) {
        int d = dst[e];
        int p = atomicAdd(&rs[1 + d], 1);
        pairs[p] = src[e];
    }
}

// ---------------- graph boundaries + Hq sentinel-row zero ----------------

__global__ void bounds_kernel(const int* __restrict__ batch, int* __restrict__ start,
                              unsigned int* __restrict__ sentinel) {
    int g = threadIdx.x;
    if (g < 32) sentinel[g] = 0u;   // zero fp8 row N_NODES (128 B)
    if (g > NG) return;
    if (g == NG) { start[NG] = N_NODES; return; }
    int lo = 0, hi = N_NODES;
    while (lo < hi) {
        int mid = (lo + hi) >> 1;
        if (batch[mid] < g) lo = mid + 1; else hi = mid;
    }
    start[g] = lo;
}

// ---------------- dense transform via MFMA: Hq = fp8( dinv * (A @ W) ) -----

template <bool IN_F32>
__global__ __launch_bounds__(512) void xw_mfma_kernel(const void* __restrict__ Xin,
                                                      const float* __restrict__ W,
                                                      const float* __restrict__ dinv,
                                                      unsigned char* __restrict__ Hq) {
    __shared__ __align__(16) unsigned short bt_hi[128 * 128];  // 32 KB, Bt[n][k]
    __shared__ __align__(16) unsigned short bt_lo[128 * 128];  // 32 KB
    __shared__ __align__(16) unsigned short atile[64 * 128];   // 16 KB, A[row][k]

    const int t = threadIdx.x;
    const int lane = t & 63;
    const int wid = t >> 6;

    #pragma unroll 4
    for (int i = 0; i < 32; ++i) {
        int idx = t + i * 512;
        int k = idx >> 7;
        int n = idx & 127;
        float w = W[idx];
        unsigned short hi = f2bf(w);
        unsigned short lo = f2bf(w - bf2f(hi));
        int byte = (n * 256 + k * 2) ^ ((n & 7) << 4);
        *(unsigned short*)((char*)bt_hi + byte) = hi;
        *(unsigned short*)((char*)bt_lo + byte) = lo;
    }

    const int mrow = (wid >> 1) * 16;
    const int ncol = (wid & 1) * 64;
    const int ar = mrow + (lane & 15);
    const int ak = (lane >> 4) * 8;

    for (int tile = blockIdx.x; tile < NTILES; tile += gridDim.x) {
        const int node0 = tile * 64;
        __syncthreads();

        #pragma unroll
        for (int p = 0; p < 2; ++p) {
            int j = t + p * 512;
            int row = j >> 4;
            int c8 = (j & 15) * 8;
            int node = node0 + row;
            short8 v = 0;
            if (IN_F32) {
                const float* X = (const float*)Xin;
                if (node < N_NODES) {
                    const float* xr = &X[(size_t)node * 128 + c8];
                    float4 a = *(const float4*)xr;
                    float4 b = *(const float4*)(xr + 4);
                    v[0] = (short)f2bf(a.x); v[1] = (short)f2bf(a.y);
                    v[2] = (short)f2bf(a.z); v[3] = (short)f2bf(a.w);
                    v[4] = (short)f2bf(b.x); v[5] = (short)f2bf(b.y);
                    v[6] = (short)f2bf(b.z); v[7] = (short)f2bf(b.w);
                }
            } else {
                const unsigned short* X = (const unsigned short*)Xin;
                if (node < N_NODES) v = *(const short8*)&X[(size_t)node * 128 + c8];
            }
            int byte = (row * 256 + c8 * 2) ^ ((row & 7) << 4);
            *(short8*)((char*)atile + byte) = v;
        }
        __syncthreads();

        f32x4 acc[4];
        #pragma unroll
        for (int nt = 0; nt < 4; ++nt) acc[nt] = 0.f;

        #pragma unroll
        for (int kc = 0; kc < 128; kc += 32) {
            short8 a = *(const short8*)((const char*)atile +
                        ((ar * 256 + (kc + ak) * 2) ^ ((ar & 7) << 4)));
            #pragma unroll
            for (int nt = 0; nt < 4; ++nt) {
                int col = ncol + nt * 16 + (lane & 15);
                int boff = (col * 256 + (kc + ak) * 2) ^ ((col & 7) << 4);
                short8 bh = *(const short8*)((const char*)bt_hi + boff);
                acc[nt] = __builtin_amdgcn_mfma_f32_16x16x32_bf16(a, bh, acc[nt], 0, 0, 0);
                short8 bl = *(const short8*)((const char*)bt_lo + boff);
                acc[nt] = __builtin_amdgcn_mfma_f32_16x16x32_bf16(a, bl, acc[nt], 0, 0, 0);
            }
        }

        // ---- store C as fp8, prescaled by dinv[node] ----
        #pragma unroll
        for (int r = 0; r < 4; ++r) {
            int node = node0 + mrow + (lane >> 4) * 4 + r;
            if (node < N_NODES) {
                float di = dinv[node];
                #pragma unroll
                for (int nt = 0; nt < 4; ++nt)
                    Hq[(size_t)node * 128 + ncol + nt * 16 + (lane & 15)] = f2fp8(acc[nt][r] * di);
            }
        }
    }
}

// ---------------- CSR gather (fp8 in, bf16 out) + fused epilogue -----------
// out[n] = relu( dinv[n] * (Hs[n] + sum_{e in in(n)} Hs[src_e]) + b ).
// Weightless: metadata is a 4 B src index; OOB lanes read the zero
// sentinel row N_NODES. One coalesced dword covers 64 edges' metadata.

#define ACC8ADD(HV)                                                        \
    {                                                                      \
        f32x2 _h0 = __builtin_amdgcn_cvt_pk_f32_fp8((int)(HV).x, false);   \
        f32x2 _h1 = __builtin_amdgcn_cvt_pk_f32_fp8((int)(HV).x, true);    \
        f32x2 _h2 = __builtin_amdgcn_cvt_pk_f32_fp8((int)(HV).y, false);   \
        f32x2 _h3 = __builtin_amdgcn_cvt_pk_f32_fp8((int)(HV).y, true);    \
        acc[0] += _h0[0]; acc[1] += _h0[1];                                \
        acc[2] += _h1[0]; acc[3] += _h1[1];                                \
        acc[4] += _h2[0]; acc[5] += _h2[1];                                \
        acc[6] += _h3[0]; acc[7] += _h3[1];                                \
    }

__global__ __launch_bounds__(256) void gather_kernel(const unsigned char* __restrict__ Hq,
                                                     const int* __restrict__ rs,
                                                     const int* __restrict__ pairs,
                                                     const float* __restrict__ dinv,
                                                     const float* __restrict__ bias,
                                                     unsigned short* __restrict__ out) {
    int node = blockIdx.x * 4 + (threadIdx.x >> 6);
    if (node >= N_NODES) return;
    const int lane = threadIdx.x & 63;
    const int g = lane >> 4;
    const int fl = lane & 15;

    int beg = rs[node];
    int end = rs[node + 1];
    int deg = end - beg;

    float acc[8];
    if (g == 0) {
        uint2 sv = *(const uint2*)&Hq[(size_t)node * 128 + fl * 8];
        f32x2 a0 = __builtin_amdgcn_cvt_pk_f32_fp8((int)sv.x, false);
        f32x2 a1 = __builtin_amdgcn_cvt_pk_f32_fp8((int)sv.x, true);
        f32x2 a2 = __builtin_amdgcn_cvt_pk_f32_fp8((int)sv.y, false);
        f32x2 a3 = __builtin_amdgcn_cvt_pk_f32_fp8((int)sv.y, true);
        acc[0] = a0[0]; acc[1] = a0[1];
        acc[2] = a1[0]; acc[3] = a1[1];
        acc[4] = a2[0]; acc[5] = a2[1];
        acc[6] = a3[0]; acc[7] = a3[1];
    } else {
        #pragma unroll
        for (int j = 0; j < 8; ++j) acc[j] = 0.f;
    }

    if (deg > 0) {
        // one coalesced metadata load covers the first min(deg,64) edges
        int pall = pairs[beg + min(lane, deg - 1)];
        int niter = (deg + 3) >> 2;          // wave-uniform

        const int j0 = g, j1 = g + 4, j2 = g + 8, j3 = g + 12;
        int s0 = (j0 < deg) ? __shfl(pall, j0) : N_NODES;
        int s1 = (j1 < deg) ? __shfl(pall, j1) : N_NODES;
        int s2 = (j2 < deg) ? __shfl(pall, j2) : N_NODES;
        int s3 = (j3 < deg) ? __shfl(pall, j3) : N_NODES;

        uint2 h0 = make_uint2(0u, 0u), h1 = h0, h2 = h0, h3 = h0;
        h0 = *(const uint2*)&Hq[(size_t)s0 * 128 + fl * 8];   // niter >= 1
        if (niter > 1) h1 = *(const uint2*)&Hq[(size_t)s1 * 128 + fl * 8];
        if (niter > 2) h2 = *(const uint2*)&Hq[(size_t)s2 * 128 + fl * 8];
        if (niter > 3) h3 = *(const uint2*)&Hq[(size_t)s3 * 128 + fl * 8];

        ACC8ADD(h0);
        ACC8ADD(h1);
        ACC8ADD(h2);
        ACC8ADD(h3);

        if (deg > 16) {                      // rare (Poisson(8): ~0.4%)
            for (int j = 16 + g; j < deg; j += 4) {
                int s = pairs[beg + j];
                uint2 hv = *(const uint2*)&Hq[(size_t)s * 128 + fl * 8];
                ACC8ADD(hv);
            }
        }
    }

    // combine the 4 edge-groups (lanes l, l+16, l+32, l+48)
    #pragma unroll
    for (int mask = 16; mask <= 32; mask <<= 1) {
        #pragma unroll
        for (int j = 0; j < 8; ++j) acc[j] += __shfl_xor(acc[j], mask);
    }

    if (g == 0) {
        float di = dinv[node];
        float4 bb0 = *(const float4*)&bias[fl * 8];
        float4 bb1 = *(const float4*)&bias[fl * 8 + 4];
        short8 o;
        o[0] = (short)f2bf(fmaxf(fmaf(acc[0], di, bb0.x), 0.f));
        o[1] = (short)f2bf(fmaxf(fmaf(acc[1], di, bb0.y), 0.f));
        o[2] = (short)f2bf(fmaxf(fmaf(acc[2], di, bb0.z), 0.f));
        o[3] = (short)f2bf(fmaxf(fmaf(acc[3], di, bb0.w), 0.f));
        o[4] = (short)f2bf(fmaxf(fmaf(acc[4], di, bb1.x), 0.f));
        o[5] = (short)f2bf(fmaxf(fmaf(acc[5], di, bb1.y), 0.f));
        o[6] = (short)f2bf(fmaxf(fmaf(acc[6], di, bb1.z), 0.f));
        o[7] = (short)f2bf(fmaxf(fmaf(acc[7], di, bb1.w), 0.f));
        *(short8*)&out[(size_t)node * 128 + fl * 8] = o;
    }
}

// ---------------- mean pool: dense segmented sum over start[] --------------

__global__ __launch_bounds__(256) void pool_kernel(const unsigned short* __restrict__ G,
                                                   const int* __restrict__ start,
                                                   float* __restrict__ sums) {
    __shared__ float red[16][132];
    int g = blockIdx.x >> 4;
    int s = blockIdx.x & 15;
    int n0 = start[g], n1 = start[g + 1];
    int slot = threadIdx.x & 15;
    int nl = threadIdx.x >> 4;

    float acc[8];
    #pragma unroll
    for (int j = 0; j < 8; ++j) acc[j] = 0.f;

    for (int node = n0 + s * 16 + nl; node < n1; node += 256) {
        short8 v = *(const short8*)&G[(size_t)node * 128 + slot * 8];
        #pragma unroll
        for (int j = 0; j < 8; ++j) acc[j] += bf2f((unsigned short)v[j]);
    }

    #pragma unroll
    for (int j = 0; j < 8; ++j) red[nl][slot * 8 + j] = acc[j];
    __syncthreads();
    #pragma unroll
    for (int off = 8; off > 0; off >>= 1) {
        if (nl < off) {
            #pragma unroll
            for (int j = 0; j < 8; ++j)
                red[nl][slot * 8 + j] += red[nl + off][slot * 8 + j];
        }
        __syncthreads();
    }
    if (nl == 0) {
        #pragma unroll
        for (int j = 0; j < 8; ++j)
            unsafeAtomicAdd(&sums[g * D + slot * 8 + j], red[0][slot * 8 + j]);
    }
}

// ---------------- final FC ----------------

__global__ void fc_kernel(const float* __restrict__ sums, const int* __restrict__ start,
                          const float* __restrict__ Wfc, const float* __restrict__ bfc,
                          float* __restrict__ out) {
    __shared__ __align__(16) float ps[D];
    int g = blockIdx.x;
    int f = threadIdx.x;
    float c = (float)max(start[g + 1] - start[g], 1);
    ps[f] = sums[g * D + f] / c;
    __syncthreads();
    float acc = bfc[f];
    #pragma unroll
    for (int k = 0; k < D; k += 4) {
        float4 pv = *(const float4*)&ps[k];
        acc += pv.x * Wfc[k * D + f] + pv.y * Wfc[(k + 1) * D + f] +
               pv.z * Wfc[(k + 2) * D + f] + pv.w * Wfc[(k + 3) * D + f];
    }
    out[g * D + f] = acc;
}

extern "C" void kernel_launch(void* const* d_in, const int* in_sizes, int n_in,
                              void* d_out, int out_size, void* d_ws, size_t ws_size,
                              hipStream_t stream) {
    const float* x   = (const float*)d_in[0];
    const int* ei    = (const int*)d_in[1];   // [2, E]
    const int* batch = (const int*)d_in[2];
    const float* W1  = (const float*)d_in[3];
    const float* b1  = (const float*)d_in[4];
    const float* W2  = (const float*)d_in[5];
    const float* b2  = (const float*)d_in[6];
    const float* Wfc = (const float*)d_in[7];
    const float* bfc = (const float*)d_in[8];
    float* out = (float*)d_out;

    const int* src = ei;
    const int* dst = ei + N_EDGES;

    // workspace layout
    unsigned char* Hq    = (unsigned char*)d_ws;                 // (N+1)*D fp8 (row N = zero sentinel)
    unsigned short* G    = (unsigned short*)(Hq + (size_t)(N_NODES + 1) * D);  // N*D bf16
    int* pairs           = (int*)(G + (size_t)N_NODES * D);      // E (src only)
    float* dinv          = (float*)(pairs + N_EDGES);            // N
    int*   deg           = (int*)(dinv + N_NODES);               // N
    int*   rs            = deg + N_NODES;                        // N+2 (start/cursor merged)
    int*   bsum          = rs + N_NODES + 4;                     // 512
    int*   start         = bsum + 512;                           // NG+1 (+pad)
    float* sums          = (float*)(start + NG + 8);             // NG*D

    hipMemsetAsync(deg, 0, N_NODES * sizeof(int), stream);
    hipMemsetAsync(sums, 0, NG * D * sizeof(float), stream);

    // --- CSR build (shared by both layers) + graph bounds + sentinel ---
    hist_kernel<<<(N_EDGES + 255) / 256, 256, 0, stream>>>(dst, deg);
    scan1_kernel<<<SCAN_NB, 256, 0, stream>>>(deg, rs, bsum, dinv);
    scan2_kernel<<<1, 512, 0, stream>>>(bsum);
    scan3_kernel<<<SCAN_NB, 256, 0, stream>>>(rs, bsum);
    fill_kernel<<<(N_EDGES + 255) / 256, 256, 0, stream>>>(src, dst, rs, pairs);
    bounds_kernel<<<1, 128, 0, stream>>>(batch, start,
                                         (unsigned int*)(Hq + (size_t)N_NODES * D));

    // --- layer 1 ---
    xw_mfma_kernel<true><<<512, 512, 0, stream>>>(x, W1, dinv, Hq);
    gather_kernel<<<(N_NODES + 3) / 4, 256, 0, stream>>>(Hq, rs, pairs, dinv, b1, G);

    // --- layer 2 ---
    xw_mfma_kernel<false><<<512, 512, 0, stream>>>(G, W2, dinv, Hq);
    gather_kernel<<<(N_NODES + 3) / 4, 256, 0, stream>>>(Hq, rs, pairs, dinv, b2, G);

    // --- mean pool + FC ---
    pool_kernel<<<NG * 16, 256, 0, stream>>>(G, start, sums);
    fc_kernel<<<NG, 128, 0, stream>>>(sums, start, Wfc, bfc, out);
}

// Round 9
// 303.169 us; speedup vs baseline: 1.0363x; 1.0363x over previous
//
#include <hip/hip_runtime.h>
#include <hip/hip_bf16.h>

#define N_NODES 100000
#define N_EDGES 800000
#define D 128
#define NG 64
#define SCAN_NB ((N_NODES + 255) / 256)   // 391
#define NTILES ((N_NODES + 63) / 64)      // 1563

typedef __attribute__((ext_vector_type(8))) short short8;
typedef __attribute__((ext_vector_type(4))) float f32x4;
typedef __attribute__((ext_vector_type(2))) float f32x2;

static __device__ __forceinline__ unsigned short f2bf(float f) {
    unsigned u = __float_as_uint(f);
    unsigned r = (u + 0x7FFF + ((u >> 16) & 1)) >> 16;   // RTN-even
    return (unsigned short)r;
}
static __device__ __forceinline__ float bf2f(unsigned short b) {
    return __uint_as_float((unsigned)b << 16);
}
static __device__ __forceinline__ unsigned char f2fp8(float v) {
    int p = __builtin_amdgcn_cvt_pk_fp8_f32(v, v, 0, false);  // RNE, OCP e4m3fn
    return (unsigned char)(p & 0xFF);
}

// ---------------- CSR build: histogram / scan(+dinv) ----------------

__global__ void hist_kernel(const int* __restrict__ dst, int* __restrict__ deg) {
    int e = blockIdx.x * blockDim.x + threadIdx.x;
    if (e < N_EDGES) atomicAdd(&deg[dst[e]], 1);
}

// writes exclusive prefix into rs[i+1]; rs[0] set by scan23.
__global__ __launch_bounds__(256) void scan1_kernel(const int* __restrict__ deg,
                                                    int* __restrict__ rs,
                                                    int* __restrict__ bsum,
                                                    float* __restrict__ dinv) {
    __shared__ int wsum[4];
    int i = blockIdx.x * 256 + threadIdx.x;
    int lane = threadIdx.x & 63;
    int wid = threadIdx.x >> 6;
    int v = (i < N_NODES) ? deg[i] : 0;
    if (i < N_NODES) dinv[i] = rsqrtf((float)v + 1.0f);  // +1 self loop
    int x = v;
    #pragma unroll
    for (int off = 1; off < 64; off <<= 1) {
        int y = __shfl_up(x, off);
        if (lane >= off) x += y;
    }
    if (lane == 63) wsum[wid] = x;
    __syncthreads();
    int add = 0;
    #pragma unroll
    for (int w = 0; w < 3; ++w) if (w < wid) add += wsum[w];
    int incl = x + add;
    if (i < N_NODES) rs[i + 1] = incl - v;
    if (threadIdx.x == 255) bsum[blockIdx.x] = incl;
}

// merged scan2+scan3 (+bounds +sentinel): every block redundantly scans
// the 391 block-sums in LDS, then fixes up its 512 rs entries.
__global__ __launch_bounds__(512) void scan23_kernel(int* __restrict__ rs,
                                                     const int* __restrict__ bsum,
                                                     const int* __restrict__ batch,
                                                     int* __restrict__ start,
                                                     unsigned int* __restrict__ sentinel) {
    __shared__ int s[512];
    int t = threadIdx.x;
    int v = (t < SCAN_NB) ? bsum[t] : 0;
    s[t] = v;
    __syncthreads();
    for (int off = 1; off < 512; off <<= 1) {
        int y = (t >= off) ? s[t - off] : 0;
        __syncthreads();
        s[t] += y;
        __syncthreads();
    }
    int i = blockIdx.x * 512 + t;
    if (i < N_NODES) {
        int c = i >> 8;                       // scan1 chunk id
        rs[i + 1] += s[c] - bsum[c];          // exclusive offset of chunk c
    }
    if (i == 0) rs[0] = 0;

    if (blockIdx.x == 0) {
        if (t < 32) sentinel[t] = 0u;         // zero fp8 sentinel row (128 B)
        if (t >= 64 && t <= 64 + NG) {
            int g = t - 64;
            if (g == NG) { start[NG] = N_NODES; }
            else {
                int lo = 0, hi = N_NODES;
                while (lo < hi) {
                    int mid = (lo + hi) >> 1;
                    if (batch[mid] < g) lo = mid + 1; else hi = mid;
                }
                start[g] = lo;
            }
        }
    }
}

// ---------------- dense transform via MFMA: Hq = fp8( dinv * (A @ W) ) -----
// DO_FILL: CSR fill scatter fused as a prologue — its atomics/stores drain
// asynchronously under the MFMA work (fill alone is latency-bound, VALU 0.4%).

template <bool IN_F32, bool DO_FILL>
__global__ __launch_bounds__(512) void xw_mfma_kernel(const void* __restrict__ Xin,
                                                      const float* __restrict__ W,
                                                      const float* __restrict__ dinv,
                                                      unsigned char* __restrict__ Hq,
                                                      const int* __restrict__ src,
                                                      const int* __restrict__ dst,
                                                      int* __restrict__ rs,
                                                      int* __restrict__ pairs) {
    __shared__ __align__(16) unsigned short bt_hi[128 * 128];  // 32 KB, Bt[n][k]
    __shared__ __align__(16) unsigned short bt_lo[128 * 128];  // 32 KB
    __shared__ __align__(16) unsigned short atile[64 * 128];   // 16 KB, A[row][k]

    const int t = threadIdx.x;
    const int lane = t & 63;
    const int wid = t >> 6;

    if (DO_FILL) {
        // grid is 512 blocks x 512 threads = 262144 threads; <=4 edges each.
        int tg = blockIdx.x * 512 + t;
        #pragma unroll
        for (int i = 0; i < 4; ++i) {
            int e = tg + i * 262144;
            if (e < N_EDGES) {
                int d = dst[e];
                int p = atomicAdd(&rs[1 + d], 1);
                pairs[p] = src[e];
            }
        }
    }

    #pragma unroll 4
    for (int i = 0; i < 32; ++i) {
        int idx = t + i * 512;
        int k = idx >> 7;
        int n = idx & 127;
        float w = W[idx];
        unsigned short hi = f2bf(w);
        unsigned short lo = f2bf(w - bf2f(hi));
        int byte = (n * 256 + k * 2) ^ ((n & 7) << 4);
        *(unsigned short*)((char*)bt_hi + byte) = hi;
        *(unsigned short*)((char*)bt_lo + byte) = lo;
    }

    const int mrow = (wid >> 1) * 16;
    const int ncol = (wid & 1) * 64;
    const int ar = mrow + (lane & 15);
    const int ak = (lane >> 4) * 8;

    for (int tile = blockIdx.x; tile < NTILES; tile += gridDim.x) {
        const int node0 = tile * 64;
        __syncthreads();

        #pragma unroll
        for (int p = 0; p < 2; ++p) {
            int j = t + p * 512;
            int row = j >> 4;
            int c8 = (j & 15) * 8;
            int node = node0 + row;
            short8 v = 0;
            if (IN_F32) {
                const float* X = (const float*)Xin;
                if (node < N_NODES) {
                    const float* xr = &X[(size_t)node * 128 + c8];
                    float4 a = *(const float4*)xr;
                    float4 b = *(const float4*)(xr + 4);
                    v[0] = (short)f2bf(a.x); v[1] = (short)f2bf(a.y);
                    v[2] = (short)f2bf(a.z); v[3] = (short)f2bf(a.w);
                    v[4] = (short)f2bf(b.x); v[5] = (short)f2bf(b.y);
                    v[6] = (short)f2bf(b.z); v[7] = (short)f2bf(b.w);
                }
            } else {
                const unsigned short* X = (const unsigned short*)Xin;
                if (node < N_NODES) v = *(const short8*)&X[(size_t)node * 128 + c8];
            }
            int byte = (row * 256 + c8 * 2) ^ ((row & 7) << 4);
            *(short8*)((char*)atile + byte) = v;
        }
        __syncthreads();

        f32x4 acc[4];
        #pragma unroll
        for (int nt = 0; nt < 4; ++nt) acc[nt] = 0.f;

        #pragma unroll
        for (int kc = 0; kc < 128; kc += 32) {
            short8 a = *(const short8*)((const char*)atile +
                        ((ar * 256 + (kc + ak) * 2) ^ ((ar & 7) << 4)));
            #pragma unroll
            for (int nt = 0; nt < 4; ++nt) {
                int col = ncol + nt * 16 + (lane & 15);
                int boff = (col * 256 + (kc + ak) * 2) ^ ((col & 7) << 4);
                short8 bh = *(const short8*)((const char*)bt_hi + boff);
                acc[nt] = __builtin_amdgcn_mfma_f32_16x16x32_bf16(a, bh, acc[nt], 0, 0, 0);
                short8 bl = *(const short8*)((const char*)bt_lo + boff);
                acc[nt] = __builtin_amdgcn_mfma_f32_16x16x32_bf16(a, bl, acc[nt], 0, 0, 0);
            }
        }

        // ---- store C as fp8, prescaled by dinv[node] ----
        #pragma unroll
        for (int r = 0; r < 4; ++r) {
            int node = node0 + mrow + (lane >> 4) * 4 + r;
            if (node < N_NODES) {
                float di = dinv[node];
                #pragma unroll
                for (int nt = 0; nt < 4; ++nt)
                    Hq[(size_t)node * 128 + ncol + nt * 16 + (lane & 15)] = f2fp8(acc[nt][r] * di);
            }
        }
    }
}

// ---------------- CSR gather (fp8 in, bf16 out) + fused epilogue -----------
// out[n] = relu( dinv[n] * (Hs[n] + sum_{e in in(n)} Hs[src_e]) + b ).

#define ACC8ADD(HV)                                                        \
    {                                                                      \
        f32x2 _h0 = __builtin_amdgcn_cvt_pk_f32_fp8((int)(HV).x, false);   \
        f32x2 _h1 = __builtin_amdgcn_cvt_pk_f32_fp8((int)(HV).x, true);    \
        f32x2 _h2 = __builtin_amdgcn_cvt_pk_f32_fp8((int)(HV).y, false);   \
        f32x2 _h3 = __builtin_amdgcn_cvt_pk_f32_fp8((int)(HV).y, true);    \
        acc[0] += _h0[0]; acc[1] += _h0[1];                                \
        acc[2] += _h1[0]; acc[3] += _h1[1];                                \
        acc[4] += _h2[0]; acc[5] += _h2[1];                                \
        acc[6] += _h3[0]; acc[7] += _h3[1];                                \
    }

__global__ __launch_bounds__(256) void gather_kernel(const unsigned char* __restrict__ Hq,
                                                     const int* __restrict__ rs,
                                                     const int* __restrict__ pairs,
                                                     const float* __restrict__ dinv,
                                                     const float* __restrict__ bias,
                                                     unsigned short* __restrict__ out) {
    int node = blockIdx.x * 4 + (threadIdx.x >> 6);
    if (node >= N_NODES) return;
    const int lane = threadIdx.x & 63;
    const int g = lane >> 4;
    const int fl = lane & 15;

    int beg = rs[node];
    int end = rs[node + 1];
    int deg = end - beg;

    float acc[8];
    if (g == 0) {
        uint2 sv = *(const uint2*)&Hq[(size_t)node * 128 + fl * 8];
        f32x2 a0 = __builtin_amdgcn_cvt_pk_f32_fp8((int)sv.x, false);
        f32x2 a1 = __builtin_amdgcn_cvt_pk_f32_fp8((int)sv.x, true);
        f32x2 a2 = __builtin_amdgcn_cvt_pk_f32_fp8((int)sv.y, false);
        f32x2 a3 = __builtin_amdgcn_cvt_pk_f32_fp8((int)sv.y, true);
        acc[0] = a0[0]; acc[1] = a0[1];
        acc[2] = a1[0]; acc[3] = a1[1];
        acc[4] = a2[0]; acc[5] = a2[1];
        acc[6] = a3[0]; acc[7] = a3[1];
    } else {
        #pragma unroll
        for (int j = 0; j < 8; ++j) acc[j] = 0.f;
    }

    if (deg > 0) {
        // one coalesced metadata load covers the first min(deg,64) edges
        int pall = pairs[beg + min(lane, deg - 1)];
        int niter = (deg + 3) >> 2;          // wave-uniform

        const int j0 = g, j1 = g + 4, j2 = g + 8, j3 = g + 12;
        int s0 = (j0 < deg) ? __shfl(pall, j0) : N_NODES;
        int s1 = (j1 < deg) ? __shfl(pall, j1) : N_NODES;
        int s2 = (j2 < deg) ? __shfl(pall, j2) : N_NODES;
        int s3 = (j3 < deg) ? __shfl(pall, j3) : N_NODES;

        uint2 h0, h1, h2, h3;
        h0 = *(const uint2*)&Hq[(size_t)s0 * 128 + fl * 8];   // niter >= 1
        if (niter > 1) h1 = *(const uint2*)&Hq[(size_t)s1 * 128 + fl * 8];
        if (niter > 2) h2 = *(const uint2*)&Hq[(size_t)s2 * 128 + fl * 8];
        if (niter > 3) h3 = *(const uint2*)&Hq[(size_t)s3 * 128 + fl * 8];

        ACC8ADD(h0);
        if (niter > 1) ACC8ADD(h1);
        if (niter > 2) ACC8ADD(h2);
        if (niter > 3) ACC8ADD(h3);

        if (deg > 16) {                      // rare (Poisson(8): ~0.4%)
            for (int j = 16 + g; j < deg; j += 4) {
                int s = pairs[beg + j];
                uint2 hv = *(const uint2*)&Hq[(size_t)s * 128 + fl * 8];
                ACC8ADD(hv);
            }
        }
    }

    // combine the 4 edge-groups (lanes l, l+16, l+32, l+48)
    #pragma unroll
    for (int mask = 16; mask <= 32; mask <<= 1) {
        #pragma unroll
        for (int j = 0; j < 8; ++j) acc[j] += __shfl_xor(acc[j], mask);
    }

    if (g == 0) {
        float di = dinv[node];
        float4 bb0 = *(const float4*)&bias[fl * 8];
        float4 bb1 = *(const float4*)&bias[fl * 8 + 4];
        short8 o;
        o[0] = (short)f2bf(fmaxf(fmaf(acc[0], di, bb0.x), 0.f));
        o[1] = (short)f2bf(fmaxf(fmaf(acc[1], di, bb0.y), 0.f));
        o[2] = (short)f2bf(fmaxf(fmaf(acc[2], di, bb0.z), 0.f));
        o[3] = (short)f2bf(fmaxf(fmaf(acc[3], di, bb0.w), 0.f));
        o[4] = (short)f2bf(fmaxf(fmaf(acc[4], di, bb1.x), 0.f));
        o[5] = (short)f2bf(fmaxf(fmaf(acc[5], di, bb1.y), 0.f));
        o[6] = (short)f2bf(fmaxf(fmaf(acc[6], di, bb1.z), 0.f));
        o[7] = (short)f2bf(fmaxf(fmaf(acc[7], di, bb1.w), 0.f));
        *(short8*)&out[(size_t)node * 128 + fl * 8] = o;
    }
}

// ---------------- mean pool: partials per (graph, sub-block), no atomics ---

__global__ __launch_bounds__(256) void pool_kernel(const unsigned short* __restrict__ G,
                                                   const int* __restrict__ start,
                                                   float* __restrict__ partial) {
    __shared__ float red[16][132];
    int g = blockIdx.x >> 4;
    int s = blockIdx.x & 15;
    int n0 = start[g], n1 = start[g + 1];
    int slot = threadIdx.x & 15;
    int nl = threadIdx.x >> 4;

    float acc[8];
    #pragma unroll
    for (int j = 0; j < 8; ++j) acc[j] = 0.f;

    for (int node = n0 + s * 16 + nl; node < n1; node += 256) {
        short8 v = *(const short8*)&G[(size_t)node * 128 + slot * 8];
        #pragma unroll
        for (int j = 0; j < 8; ++j) acc[j] += bf2f((unsigned short)v[j]);
    }

    #pragma unroll
    for (int j = 0; j < 8; ++j) red[nl][slot * 8 + j] = acc[j];
    __syncthreads();
    #pragma unroll
    for (int off = 8; off > 0; off >>= 1) {
        if (nl < off) {
            #pragma unroll
            for (int j = 0; j < 8; ++j)
                red[nl][slot * 8 + j] += red[nl + off][slot * 8 + j];
        }
        __syncthreads();
    }
    if (nl == 0) {
        float* prow = &partial[(size_t)blockIdx.x * D + slot * 8];
        *(float4*)&prow[0] = *(const float4*)&red[0][slot * 8];
        *(float4*)&prow[4] = *(const float4*)&red[0][slot * 8 + 4];
    }
}

// ---------------- final FC (reduces the 16 partials) ----------------

__global__ void fc_kernel(const float* __restrict__ partial, const int* __restrict__ start,
                          const float* __restrict__ Wfc, const float* __restrict__ bfc,
                          float* __restrict__ out) {
    __shared__ __align__(16) float ps[D];
    int g = blockIdx.x;
    int f = threadIdx.x;
    float c = (float)max(start[g + 1] - start[g], 1);
    float accp = 0.f;
    #pragma unroll
    for (int s = 0; s < 16; ++s) accp += partial[(size_t)(g * 16 + s) * D + f];
    ps[f] = accp / c;
    __syncthreads();
    float acc = bfc[f];
    #pragma unroll
    for (int k = 0; k < D; k += 4) {
        float4 pv = *(const float4*)&ps[k];
        acc += pv.x * Wfc[k * D + f] + pv.y * Wfc[(k + 1) * D + f] +
               pv.z * Wfc[(k + 2) * D + f] + pv.w * Wfc[(k + 3) * D + f];
    }
    out[g * D + f] = acc;
}

extern "C" void kernel_launch(void* const* d_in, const int* in_sizes, int n_in,
                              void* d_out, int out_size, void* d_ws, size_t ws_size,
                              hipStream_t stream) {
    const float* x   = (const float*)d_in[0];
    const int* ei    = (const int*)d_in[1];   // [2, E]
    const int* batch = (const int*)d_in[2];
    const float* W1  = (const float*)d_in[3];
    const float* b1  = (const float*)d_in[4];
    const float* W2  = (const float*)d_in[5];
    const float* b2  = (const float*)d_in[6];
    const float* Wfc = (const float*)d_in[7];
    const float* bfc = (const float*)d_in[8];
    float* out = (float*)d_out;

    const int* src = ei;
    const int* dst = ei + N_EDGES;

    // workspace layout
    unsigned char* Hq    = (unsigned char*)d_ws;                 // (N+1)*D fp8 (row N = zero sentinel)
    unsigned short* G    = (unsigned short*)(Hq + (size_t)(N_NODES + 1) * D);  // N*D bf16
    int* pairs           = (int*)(G + (size_t)N_NODES * D);      // E (src only)
    float* dinv          = (float*)(pairs + N_EDGES);            // N
    int*   deg           = (int*)(dinv + N_NODES);               // N
    int*   rs            = deg + N_NODES;                        // N+2 (start/cursor merged)
    int*   bsum          = rs + N_NODES + 4;                     // 512
    int*   start         = bsum + 512;                           // NG+1 (+pad)
    float* partial       = (float*)(start + NG + 8);             // NG*16*D

    hipMemsetAsync(deg, 0, N_NODES * sizeof(int), stream);

    // --- CSR build prep (hist + scans; fill is fused into xw1) ---
    hist_kernel<<<(N_EDGES + 255) / 256, 256, 0, stream>>>(dst, deg);
    scan1_kernel<<<SCAN_NB, 256, 0, stream>>>(deg, rs, bsum, dinv);
    scan23_kernel<<<(N_NODES + 511) / 512, 512, 0, stream>>>(
        rs, bsum, batch, start, (unsigned int*)(Hq + (size_t)N_NODES * D));

    // --- layer 1 (CSR fill fused as prologue) ---
    xw_mfma_kernel<true, true><<<512, 512, 0, stream>>>(x, W1, dinv, Hq, src, dst, rs, pairs);
    gather_kernel<<<(N_NODES + 3) / 4, 256, 0, stream>>>(Hq, rs, pairs, dinv, b1, G);

    // --- layer 2 ---
    xw_mfma_kernel<false, false><<<512, 512, 0, stream>>>(G, W2, dinv, Hq, src, dst, rs, pairs);
    gather_kernel<<<(N_NODES + 3) / 4, 256, 0, stream>>>(Hq, rs, pairs, dinv, b2, G);

    // --- mean pool + FC ---
    pool_kernel<<<NG * 16, 256, 0, stream>>>(G, start, partial);
    fc_kernel<<<NG, 128, 0, stream>>>(partial, start, Wfc, bfc, out);
}